// Round 8
// baseline (565.930 us; speedup 1.0000x reference)
//
#include <hip/hip_runtime.h>
#include <hip/hip_bf16.h>

// CustomQuantLinear: out[m][n] = scale[n] * sum_k x[m][k]*(w[n][k]-zp[n]) + bias[n]
// M=8192, N=11008, K=4096.
// R7 -> R8: neither pipe saturated (MFMA 41%, LDS 60%) -> intra-wave
// serialization {ds_read; lgkm; bar; MFMA} is the wall. Register frag
// double-buffer: reads(g+1) issue under MFMA(g) (no lgkm before MFMA),
// ONE barrier per group, stage 3-ahead into 3-slot ring (96KB), counted
// vmcnt(4). 256^2 tile, 8 waves, 128x64/wave, 1 block/CU (reg budget 256).
// Ledger: stage(g+3)->slot g%3 (tile-g reads reg-secured via lgkm(0) before
// end-of-(g-1) barrier); vmcnt(4) at end of g forces stage(g+2) landed
// (newest 4 = stage(g+3)) -> published for reads(g+2) in group g+1.

#define MDIM 8192
#define NDIM 11008
#define KDIM 4096

#define BM 256
#define BN 256
#define BK 64
#define KT (KDIM / BK)   // 64
#define NTM (MDIM / BM)  // 32
#define NTN (NDIM / BN)  // 43
#define NWG (NTM * NTN)  // 1376 = 8*172

typedef signed char i8;
typedef int i32x4 __attribute__((ext_vector_type(4)));

// ---------- prep kernels ----------

__global__ void conv_w8(const int* __restrict__ w, i8* __restrict__ w8) {
    const size_t e = ((size_t)blockIdx.x * 256 + threadIdx.x) << 4;
    const int4 a = *(const int4*)(w + e);
    const int4 b = *(const int4*)(w + e + 4);
    const int4 c = *(const int4*)(w + e + 8);
    const int4 d = *(const int4*)(w + e + 12);
    i8 q[16];
    q[0] = (i8)a.x; q[1] = (i8)a.y; q[2] = (i8)a.z; q[3] = (i8)a.w;
    q[4] = (i8)b.x; q[5] = (i8)b.y; q[6] = (i8)b.z; q[7] = (i8)b.w;
    q[8] = (i8)c.x; q[9] = (i8)c.y; q[10] = (i8)c.z; q[11] = (i8)c.w;
    q[12] = (i8)d.x; q[13] = (i8)d.y; q[14] = (i8)d.z; q[15] = (i8)d.w;
    *(int4*)(w8 + e) = *(const int4*)q;
}

__global__ __launch_bounds__(256) void conv_xq(const float* __restrict__ x,
                                               i8* __restrict__ xq,
                                               float* __restrict__ sx,
                                               float* __restrict__ xs) {
    __shared__ float ramax[4], rsum[4];
    const int row = blockIdx.x;
    const float* xr = x + (size_t)row * KDIM;
    const int t = threadIdx.x;
    const float4* p = (const float4*)xr + (t << 2);
    float4 v0 = p[0], v1 = p[1], v2 = p[2], v3 = p[3];
    float amax = 0.f, sum = 0.f;
    float vv[16] = {v0.x, v0.y, v0.z, v0.w, v1.x, v1.y, v1.z, v1.w,
                    v2.x, v2.y, v2.z, v2.w, v3.x, v3.y, v3.z, v3.w};
#pragma unroll
    for (int i = 0; i < 16; ++i) {
        amax = fmaxf(amax, fabsf(vv[i]));
        sum += vv[i];
    }
#pragma unroll
    for (int off = 32; off > 0; off >>= 1) {
        amax = fmaxf(amax, __shfl_down(amax, off, 64));
        sum += __shfl_down(sum, off, 64);
    }
    if ((t & 63) == 0) { ramax[t >> 6] = amax; rsum[t >> 6] = sum; }
    __syncthreads();
    amax = fmaxf(fmaxf(ramax[0], ramax[1]), fmaxf(ramax[2], ramax[3]));
    sum = (rsum[0] + rsum[1]) + (rsum[2] + rsum[3]);
    const float inv = (amax > 0.f) ? 127.0f / amax : 0.f;
    if (t == 0) {
        sx[row] = amax * (1.0f / 127.0f);
        xs[row] = sum;
    }
    i8 q[16];
#pragma unroll
    for (int i = 0; i < 16; ++i) q[i] = (i8)(int)rintf(vv[i] * inv);
    *(int4*)(xq + (size_t)row * KDIM + (t << 4)) = *(const int4*)q;
}

// ---------- GEMM ----------

__device__ __forceinline__ void gload16(const i8* g, i8* l) {
    __builtin_amdgcn_global_load_lds(
        (const __attribute__((address_space(1))) unsigned int*)g,
        (__attribute__((address_space(3))) unsigned int*)l, 16, 0, 0);
}

// stage one K-tile (A[256][64] + B[256][64] = 32KB): 4 loads/thread
#define STAGE(T) do { const int _s = (T) % 3; const size_t _k = (size_t)(T) * BK; \
    gload16(gA0 + _k, &SH[_s][0][wid * 1024]);                                    \
    gload16(gA1 + _k, &SH[_s][0][8192 + wid * 1024]);                             \
    gload16(gB0 + _k, &SH[_s][1][wid * 1024]);                                    \
    gload16(gB1 + _k, &SH[_s][1][8192 + wid * 1024]); } while (0)

#define READS(T, FA, FB) do {                                                     \
    const i8* _sA = &SH[(T) % 3][0][0];                                           \
    const i8* _sB = &SH[(T) % 3][1][0];                                           \
    _Pragma("unroll") for (int _f = 0; _f < 8; ++_f)                              \
        FA[_f] = *(const i32x4*)(_sA + aoff + _f * 1024);                         \
    _Pragma("unroll") for (int _f = 0; _f < 4; ++_f)                              \
        FB[_f] = *(const i32x4*)(_sB + boff + _f * 1024); } while (0)

#define MFMAS(FA, FB) do {                                                        \
    __builtin_amdgcn_s_setprio(1);                                                \
    _Pragma("unroll") for (int _i = 0; _i < 8; ++_i)                              \
    _Pragma("unroll") for (int _j = 0; _j < 4; ++_j)                              \
        acc[_i][_j] = __builtin_amdgcn_mfma_i32_16x16x64_i8(                      \
            FA[_i], FB[_j], acc[_i][_j], 0, 0, 0);                                \
    __builtin_amdgcn_s_setprio(0); } while (0)

#define VM4 asm volatile("s_waitcnt vmcnt(4)" ::: "memory")
#define VM0 asm volatile("s_waitcnt vmcnt(0)" ::: "memory")
#define LG0 asm volatile("s_waitcnt lgkmcnt(0)" ::: "memory")

// group g: stage(g+3); reads(g+1) under MFMA(g); counted wait; 1 barrier.
#define GROUPX(T, FAc, FBc, FAn, FBn, DO_STAGE, DO_READ, WAIT) do {               \
    if (DO_STAGE) STAGE((T) + 3);                                                 \
    if (DO_READ) READS((T) + 1, FAn, FBn);                                        \
    MFMAS(FAc, FBc);                                                              \
    WAIT;                                                                         \
    LG0;                                                                          \
    __builtin_amdgcn_s_barrier(); } while (0)

__global__ __launch_bounds__(512, 2) void gemm_q(const i8* __restrict__ Xq,
                                                 const i8* __restrict__ Wq,
                                                 const float* __restrict__ sx,
                                                 const float* __restrict__ xs,
                                                 const float* __restrict__ scale,
                                                 const int* __restrict__ zp,
                                                 const float* __restrict__ bias,
                                                 float* __restrict__ out) {
    __shared__ __align__(16) i8 SH[3][2][16384];  // 3-slot ring, 96 KiB

    const int tid = threadIdx.x;
    const int wid = tid >> 6;
    const int lane = tid & 63;

    // bijective XCD raster (1376 = 8*172): xcd owns 4 consecutive M-tiles
    const int bid = blockIdx.x;
    const int pm = ((bid & 7) << 2) | ((bid >> 3) & 3);
    const int pn = bid >> 5;
    const int bm0 = pm * BM;
    const int bn0 = pn * BN;

    // staging source: row = tid>>2 (+128), col pre-swizzled so that
    // physical[P] = logical[P ^ ((row&8)<<2)] with linear gload_lds dest.
    const int srow = tid >> 2;
    const int scol = ((tid & 3) << 4) ^ (((tid >> 5) & 1) << 5);
    const i8* gA0 = Xq + (size_t)(bm0 + srow) * KDIM + scol;
    const i8* gA1 = gA0 + (size_t)128 * KDIM;
    const i8* gB0 = Wq + (size_t)(bn0 + srow) * KDIM + scol;
    const i8* gB1 = gB0 + (size_t)128 * KDIM;

    // wave map: 2M x 4N, per-wave output 128x64
    const int wm = wid >> 2, wn = wid & 3;
    const int lr = lane & 15;
    const int kb = (lane >> 4) << 4;            // 0,16,32,48 byte col
    const int swz = (lr & 8) << 2;              // row bit3 -> byte bit5
    const int aoff = (((wm * 128 + lr) << 6) + kb) ^ swz;
    const int boff = (((wn * 64 + lr) << 6) + kb) ^ swz;

    i32x4 acc[8][4];
#pragma unroll
    for (int i = 0; i < 8; ++i)
#pragma unroll
        for (int j = 0; j < 4; ++j) acc[i][j] = (i32x4){0, 0, 0, 0};

    i32x4 FA0[8], FB0[4], FA1[8], FB1[4];

    // prologue: stage tiles 0,1,2 (12 loads); publish 0; read 0; publish 1.
    STAGE(0); STAGE(1); STAGE(2);
    asm volatile("s_waitcnt vmcnt(8)" ::: "memory");   // stage(0) landed
    __builtin_amdgcn_s_barrier();                      // publish stage(0)
    READS(0, FA0, FB0);
    LG0;                                               // reads(0) in regs
    VM4;                                               // stage(1) landed
    __builtin_amdgcn_s_barrier();                      // publish stage(1)

    for (int t = 0; t < 60; t += 2) {   // groups 0..59, stages 3..62
        GROUPX(t,     FA0, FB0, FA1, FB1, true, true, VM4);
        GROUPX(t + 1, FA1, FB1, FA0, FB0, true, true, VM4);
    }
    GROUPX(60, FA0, FB0, FA1, FB1, true,  true,  VM4);   // stages 63
    GROUPX(61, FA1, FB1, FA0, FB0, false, true,  VM0);   // publish stage(63)
    GROUPX(62, FA0, FB0, FA1, FB1, false, true,  (void)0);
    GROUPX(63, FA1, FB1, FA0, FB0, false, false, (void)0);

    // epilogue: C/D layout col = lane&15, row = (lane>>4)*4 + reg
    const int rr = (lane >> 4) << 2;
#pragma unroll
    for (int j = 0; j < 4; ++j) {
        const int n = bn0 + wn * 64 + j * 16 + lr;
        const float sc = scale[n];
        const float zpn = (float)zp[n];
        const float bi = bias[n];
#pragma unroll
        for (int i = 0; i < 8; ++i) {
            const int m = bm0 + wm * 128 + i * 16 + rr;
#pragma unroll
            for (int r = 0; r < 4; ++r) {
                const int mm = m + r;
                const float d = (float)acc[i][j][r];
                out[(size_t)mm * NDIM + n] = sc * (sx[mm] * d - zpn * xs[mm]) + bi;
            }
        }
    }
}

// ---------- fallback (ws too small) ----------

__global__ void naive_q(const float* __restrict__ x, const int* __restrict__ wq,
                        const float* __restrict__ scale, const int* __restrict__ zp,
                        const float* __restrict__ bias, float* __restrict__ out) {
    const long long idx = (long long)blockIdx.x * 256 + threadIdx.x;
    if (idx >= (long long)MDIM * NDIM) return;
    const int m = (int)(idx / NDIM);
    const int n = (int)(idx % NDIM);
    const float* xr = x + (long long)m * KDIM;
    const int* wr = wq + (long long)n * KDIM;
    float dot = 0.f, xsum = 0.f;
    for (int k = 0; k < KDIM; ++k) {
        dot += xr[k] * (float)wr[k];
        xsum += xr[k];
    }
    out[idx] = scale[n] * (dot - (float)zp[n] * xsum) + bias[n];
}

extern "C" void kernel_launch(void* const* d_in, const int* in_sizes, int n_in,
                              void* d_out, int out_size, void* d_ws, size_t ws_size,
                              hipStream_t stream) {
    const float* x = (const float*)d_in[0];
    const int* wq = (const int*)d_in[1];
    const float* scale = (const float*)d_in[2];
    const int* zp = (const int*)d_in[3];
    const float* bias = (const float*)d_in[4];
    float* out = (float*)d_out;

    const size_t w8_bytes = (size_t)NDIM * KDIM;      // 45,088,768
    const size_t xq_bytes = (size_t)MDIM * KDIM;      // 33,554,432
    const size_t row_bytes = (size_t)MDIM * 4;        // 32,768
    const size_t need = w8_bytes + xq_bytes + 2 * row_bytes;

    if (ws_size >= need) {
        i8* w8 = (i8*)d_ws;
        i8* xq8 = (i8*)((char*)d_ws + w8_bytes);
        float* sx = (float*)((char*)d_ws + w8_bytes + xq_bytes);
        float* xs = (float*)((char*)d_ws + w8_bytes + xq_bytes + row_bytes);
        conv_w8<<<(unsigned)(w8_bytes / 16 / 256), 256, 0, stream>>>(wq, w8);
        conv_xq<<<MDIM, 256, 0, stream>>>(x, xq8, sx, xs);
        gemm_q<<<NWG, 512, 0, stream>>>(xq8, w8, sx, xs, scale, zp, bias, out);
    } else {
        const long long total = (long long)MDIM * NDIM;
        naive_q<<<(unsigned)((total + 255) / 256), 256, 0, stream>>>(
            x, wq, scale, zp, bias, out);
    }
}

// Round 9
// 551.076 us; speedup vs baseline: 1.0270x; 1.0270x over previous
//
#include <hip/hip_runtime.h>
#include <hip/hip_bf16.h>

// CustomQuantLinear: out[m][n] = scale[n] * sum_k x[m][k]*(w[n][k]-zp[n]) + bias[n]
// M=8192, N=11008, K=4096.
// R8 -> R9: four coarse schedules all hit the same ~3200cyc/group wall
// (MFMA 1306 + LDS ~1500 serialized). Faithful m201 8-phase quadrant port:
// per K-tile-pair, 8 phases of {quadrant reads (6/2/4/0 b128); 1 gload_lds;
// barrier; lgkm0; setprio; 8 MFMA; setprio; [vmcnt(4) @ P4/P8]; barrier}.
// 4-slot ring; pair p stages tile 2p+3 (P1-4) and 2p+4 (P5-8).
// Also: conv_w8 + conv_xq fused into one `prep` launch.

#define MDIM 8192
#define NDIM 11008
#define KDIM 4096

#define BM 256
#define BN 256
#define BK 64
#define KT (KDIM / BK)   // 64 tiles = 32 pairs
#define NTM (MDIM / BM)  // 32
#define NTN (NDIM / BN)  // 43
#define NWG (NTM * NTN)  // 1376 = 8*172

typedef signed char i8;
typedef int i32x4 __attribute__((ext_vector_type(4)));

// ---------- fused prep kernel ----------
// blocks [0, MDIM): per-row x quant (+absmax scale, fp32 rowsum)
// blocks [MDIM, MDIM+11008): w int32 -> int8 pack (16 elems/thread)

__global__ __launch_bounds__(256) void prep(const float* __restrict__ x,
                                            const int* __restrict__ w,
                                            i8* __restrict__ xq,
                                            float* __restrict__ sx,
                                            float* __restrict__ xs,
                                            i8* __restrict__ w8) {
    const int t = threadIdx.x;
    if (blockIdx.x < MDIM) {
        __shared__ float ramax[4], rsum[4];
        const int row = blockIdx.x;
        const float* xr = x + (size_t)row * KDIM;
        const float4* p = (const float4*)xr + (t << 2);
        float4 v0 = p[0], v1 = p[1], v2 = p[2], v3 = p[3];
        float amax = 0.f, sum = 0.f;
        float vv[16] = {v0.x, v0.y, v0.z, v0.w, v1.x, v1.y, v1.z, v1.w,
                        v2.x, v2.y, v2.z, v2.w, v3.x, v3.y, v3.z, v3.w};
#pragma unroll
        for (int i = 0; i < 16; ++i) {
            amax = fmaxf(amax, fabsf(vv[i]));
            sum += vv[i];
        }
#pragma unroll
        for (int off = 32; off > 0; off >>= 1) {
            amax = fmaxf(amax, __shfl_down(amax, off, 64));
            sum += __shfl_down(sum, off, 64);
        }
        if ((t & 63) == 0) { ramax[t >> 6] = amax; rsum[t >> 6] = sum; }
        __syncthreads();
        amax = fmaxf(fmaxf(ramax[0], ramax[1]), fmaxf(ramax[2], ramax[3]));
        sum = (rsum[0] + rsum[1]) + (rsum[2] + rsum[3]);
        const float inv = (amax > 0.f) ? 127.0f / amax : 0.f;
        if (t == 0) {
            sx[row] = amax * (1.0f / 127.0f);
            xs[row] = sum;
        }
        i8 q[16];
#pragma unroll
        for (int i = 0; i < 16; ++i) q[i] = (i8)(int)rintf(vv[i] * inv);
        *(int4*)(xq + (size_t)row * KDIM + (t << 4)) = *(const int4*)q;
    } else {
        const size_t e = (((size_t)(blockIdx.x - MDIM) * 256 + t) << 4);
        const int4 a = *(const int4*)(w + e);
        const int4 b = *(const int4*)(w + e + 4);
        const int4 c = *(const int4*)(w + e + 8);
        const int4 d = *(const int4*)(w + e + 12);
        i8 q[16];
        q[0] = (i8)a.x; q[1] = (i8)a.y; q[2] = (i8)a.z; q[3] = (i8)a.w;
        q[4] = (i8)b.x; q[5] = (i8)b.y; q[6] = (i8)b.z; q[7] = (i8)b.w;
        q[8] = (i8)c.x; q[9] = (i8)c.y; q[10] = (i8)c.z; q[11] = (i8)c.w;
        q[12] = (i8)d.x; q[13] = (i8)d.y; q[14] = (i8)d.z; q[15] = (i8)d.w;
        *(int4*)(w8 + e) = *(const int4*)q;
    }
}

// ---------- GEMM ----------

__device__ __forceinline__ void gload16(const i8* g, i8* l) {
    __builtin_amdgcn_global_load_lds(
        (const __attribute__((address_space(1))) unsigned int*)g,
        (__attribute__((address_space(3))) unsigned int*)l, 16, 0, 0);
}

// one of the 4 staging loads of tile T (A0/A1/B0/B1), IDX literal
#define SG(T, IDX) do { const int _s = (T) & 3; const size_t _k = (size_t)(T) * BK; \
    if ((IDX) == 0)      gload16(gA0 + _k, &SH[_s][0][wid * 1024]);                 \
    else if ((IDX) == 1) gload16(gA1 + _k, &SH[_s][0][8192 + wid * 1024]);          \
    else if ((IDX) == 2) gload16(gB0 + _k, &SH[_s][1][wid * 1024]);                 \
    else                 gload16(gB1 + _k, &SH[_s][1][8192 + wid * 1024]); } while (0)

#define SLOTA(T) (&SH[(T) & 3][0][0])
#define SLOTB(T) (&SH[(T) & 3][1][0])

#define RD1(T) do { const i8* _sA = SLOTA(T); const i8* _sB = SLOTB(T);            \
    _Pragma("unroll") for (int _f = 0; _f < 4; ++_f)                               \
        a0[_f] = *(const i32x4*)(_sA + aoff + _f * 1024);                          \
    _Pragma("unroll") for (int _j = 0; _j < 2; ++_j)                               \
        b01[_j] = *(const i32x4*)(_sB + boff + _j * 1024); } while (0)

#define RD2(T) do { const i8* _sB = SLOTB(T);                                      \
    _Pragma("unroll") for (int _j = 0; _j < 2; ++_j)                               \
        b23[_j] = *(const i32x4*)(_sB + boff + (_j + 2) * 1024); } while (0)

#define RD3(T) do { const i8* _sA = SLOTA(T);                                      \
    _Pragma("unroll") for (int _f = 0; _f < 4; ++_f)                               \
        a1[_f] = *(const i32x4*)(_sA + aoff + (_f + 4) * 1024); } while (0)

// 8-MFMA quadrant: rows IOFF..IOFF+3, cols JOFF..JOFF+1
#define MQ(AF, BF, IOFF, JOFF) do {                                                \
    _Pragma("unroll") for (int _i = 0; _i < 4; ++_i)                               \
    _Pragma("unroll") for (int _j = 0; _j < 2; ++_j)                               \
        acc[_i + (IOFF)][_j + (JOFF)] = __builtin_amdgcn_mfma_i32_16x16x64_i8(     \
            AF[_i], BF[_j], acc[_i + (IOFF)][_j + (JOFF)], 0, 0, 0); } while (0)

#define NOPX ((void)0)
#define VM4 asm volatile("s_waitcnt vmcnt(4)" ::: "memory")
#define VM0 asm volatile("s_waitcnt vmcnt(0)" ::: "memory")

// phase: {reads; 1 stage; barrier; lgkm0; setprio; 8 MFMA; setprio; [vm]; barrier}
#define PH(RDS, STG, MMS, TWS) do { RDS; STG;                                      \
    __builtin_amdgcn_s_barrier();                                                  \
    asm volatile("s_waitcnt lgkmcnt(0)" ::: "memory");                             \
    __builtin_amdgcn_s_setprio(1); MMS; __builtin_amdgcn_s_setprio(0);             \
    TWS; __builtin_amdgcn_s_barrier(); } while (0)

// pair: tiles T, T+1; stages tile T+3 across P1-4, tile T+4 across P5-8
#define PAIR(T, SA, SB, W4, W8) do {                                               \
    i32x4 a0[4], a1[4], b01[2], b23[2];                                            \
    PH(RD1(T), if (SA) { SG((T) + 3, 0); }, MQ(a0, b01, 0, 0), NOPX);              \
    PH(RD2(T), if (SA) { SG((T) + 3, 1); }, MQ(a0, b23, 0, 2), NOPX);              \
    PH(RD3(T), if (SA) { SG((T) + 3, 2); }, MQ(a1, b01, 4, 0), NOPX);              \
    PH(NOPX,   if (SA) { SG((T) + 3, 3); }, MQ(a1, b23, 4, 2), W4);                \
    PH(RD1((T) + 1), if (SB) { SG((T) + 4, 0); }, MQ(a0, b01, 0, 0), NOPX);        \
    PH(RD2((T) + 1), if (SB) { SG((T) + 4, 1); }, MQ(a0, b23, 0, 2), NOPX);        \
    PH(RD3((T) + 1), if (SB) { SG((T) + 4, 2); }, MQ(a1, b01, 4, 0), NOPX);        \
    PH(NOPX,         if (SB) { SG((T) + 4, 3); }, MQ(a1, b23, 4, 2), W8);          \
} while (0)

__global__ __launch_bounds__(512, 2) void gemm_q(const i8* __restrict__ Xq,
                                                 const i8* __restrict__ Wq,
                                                 const float* __restrict__ sx,
                                                 const float* __restrict__ xs,
                                                 const float* __restrict__ scale,
                                                 const int* __restrict__ zp,
                                                 const float* __restrict__ bias,
                                                 float* __restrict__ out) {
    __shared__ __align__(16) i8 SH[4][2][16384];  // 4-slot ring, 128 KiB

    const int tid = threadIdx.x;
    const int wid = tid >> 6;
    const int lane = tid & 63;

    // bijective XCD raster (1376 = 8*172)
    const int bid = blockIdx.x;
    const int pm = ((bid & 7) << 2) | ((bid >> 3) & 3);
    const int pn = bid >> 5;
    const int bm0 = pm * BM;
    const int bn0 = pn * BN;

    // staging source: row = tid>>2 (+128), col pre-swizzled so that
    // physical[P] = logical[P ^ ((row&8)<<2)] with linear gload_lds dest.
    const int srow = tid >> 2;
    const int scol = ((tid & 3) << 4) ^ (((tid >> 5) & 1) << 5);
    const i8* gA0 = Xq + (size_t)(bm0 + srow) * KDIM + scol;
    const i8* gA1 = gA0 + (size_t)128 * KDIM;
    const i8* gB0 = Wq + (size_t)(bn0 + srow) * KDIM + scol;
    const i8* gB1 = gB0 + (size_t)128 * KDIM;

    // wave map: 2M x 4N, per-wave output 128x64
    const int wm = wid >> 2, wn = wid & 3;
    const int lr = lane & 15;
    const int kb = (lane >> 4) << 4;            // 0,16,32,48 byte col
    const int swz = (lr & 8) << 2;              // row bit3 -> byte bit5
    const int aoff = (((wm * 128 + lr) << 6) + kb) ^ swz;
    const int boff = (((wn * 64 + lr) << 6) + kb) ^ swz;

    i32x4 acc[8][4];
#pragma unroll
    for (int i = 0; i < 8; ++i)
#pragma unroll
        for (int j = 0; j < 4; ++j) acc[i][j] = (i32x4){0, 0, 0, 0};

    // prologue: stage tiles 0,1,2; tile 0 landed at vmcnt(8); publish.
    SG(0, 0); SG(0, 1); SG(0, 2); SG(0, 3);
    SG(1, 0); SG(1, 1); SG(1, 2); SG(1, 3);
    SG(2, 0); SG(2, 1); SG(2, 2); SG(2, 3);
    asm volatile("s_waitcnt vmcnt(8)" ::: "memory");
    __builtin_amdgcn_s_barrier();

    for (int p = 0; p < 30; ++p) {        // pairs 0..29: stage tiles 3..62
        PAIR(2 * p, true, true, VM4, VM4);
    }
    PAIR(60, true, false, VM4, VM0);      // stages tile 63, drains all
    PAIR(62, false, false, NOPX, NOPX);   // tiles 62,63, wait-free

    // epilogue: C/D layout col = lane&15, row = (lane>>4)*4 + reg
    const int rr = (lane >> 4) << 2;
#pragma unroll
    for (int j = 0; j < 4; ++j) {
        const int n = bn0 + wn * 64 + j * 16 + lr;
        const float sc = scale[n];
        const float zpn = (float)zp[n];
        const float bi = bias[n];
#pragma unroll
        for (int i = 0; i < 8; ++i) {
            const int m = bm0 + wm * 128 + i * 16 + rr;
#pragma unroll
            for (int r = 0; r < 4; ++r) {
                const int mm = m + r;
                const float d = (float)acc[i][j][r];
                out[(size_t)mm * NDIM + n] = sc * (sx[mm] * d - zpn * xs[mm]) + bi;
            }
        }
    }
}

// ---------- fallback (ws too small) ----------

__global__ void naive_q(const float* __restrict__ x, const int* __restrict__ wq,
                        const float* __restrict__ scale, const int* __restrict__ zp,
                        const float* __restrict__ bias, float* __restrict__ out) {
    const long long idx = (long long)blockIdx.x * 256 + threadIdx.x;
    if (idx >= (long long)MDIM * NDIM) return;
    const int m = (int)(idx / NDIM);
    const int n = (int)(idx % NDIM);
    const float* xr = x + (long long)m * KDIM;
    const int* wr = wq + (long long)n * KDIM;
    float dot = 0.f, xsum = 0.f;
    for (int k = 0; k < KDIM; ++k) {
        dot += xr[k] * (float)wr[k];
        xsum += xr[k];
    }
    out[idx] = scale[n] * (dot - (float)zp[n] * xsum) + bias[n];
}

extern "C" void kernel_launch(void* const* d_in, const int* in_sizes, int n_in,
                              void* d_out, int out_size, void* d_ws, size_t ws_size,
                              hipStream_t stream) {
    const float* x = (const float*)d_in[0];
    const int* wq = (const int*)d_in[1];
    const float* scale = (const float*)d_in[2];
    const int* zp = (const int*)d_in[3];
    const float* bias = (const float*)d_in[4];
    float* out = (float*)d_out;

    const size_t w8_bytes = (size_t)NDIM * KDIM;      // 45,088,768
    const size_t xq_bytes = (size_t)MDIM * KDIM;      // 33,554,432
    const size_t row_bytes = (size_t)MDIM * 4;        // 32,768
    const size_t need = w8_bytes + xq_bytes + 2 * row_bytes;

    if (ws_size >= need) {
        i8* w8 = (i8*)d_ws;
        i8* xq8 = (i8*)((char*)d_ws + w8_bytes);
        float* sx = (float*)((char*)d_ws + w8_bytes + xq_bytes);
        float* xs = (float*)((char*)d_ws + w8_bytes + xq_bytes + row_bytes);
        // fused prep: blocks [0,MDIM) quantize x rows; [MDIM, MDIM+NDIM) pack w
        prep<<<MDIM + NDIM, 256, 0, stream>>>(x, wq, xq8, sx, xs, w8);
        gemm_q<<<NWG, 512, 0, stream>>>(xq8, w8, sx, xs, scale, zp, bias, out);
    } else {
        const long long total = (long long)MDIM * NDIM;
        naive_q<<<(unsigned)((total + 255) / 256), 256, 0, stream>>>(
            x, wq, scale, zp, bias, out);
    }
}

// Round 10
// 535.976 us; speedup vs baseline: 1.0559x; 1.0282x over previous
//
#include <hip/hip_runtime.h>
#include <hip/hip_bf16.h>

// CustomQuantLinear: out[m][n] = scale[n] * sum_k x[m][k]*(w[n][k]-zp[n]) + bias[n]
// M=8192, N=11008, K=4096.
// R9 -> R10: consolidation. Five schedules share a ~3300cyc/K-tile wall
// (i8 fills 1306 of it -> 36% MfmaUtil; same wall as m201's bf16 at 62%).
// Take the best measured pieces: R7 geometry (BM256xBN128, 2752 blocks ->
// 2.3% tail, 2 blocks/CU, 3-slot ring, vmcnt(3)) + R9's fused prep.
// One new experiment: co-resident-block phase stagger -- odd dispatch-round
// blocks s_sleep ~768cyc before staging so paired blocks anti-phase their
// LDS/MFMA bursts (pairing heuristic (bid>>8)&1; timing-only, exact math).

#define MDIM 8192
#define NDIM 11008
#define KDIM 4096

#define BM 256
#define BN 128
#define BK 64
#define KT (KDIM / BK)   // 64
#define NTM (MDIM / BM)  // 32
#define NTN (NDIM / BN)  // 86
#define NWG (NTM * NTN)  // 2752 = 8*344

#define SLOT 24576       // 16KB A + 8KB B
#define BOFFS 16384      // B region offset within slot

typedef signed char i8;
typedef int i32x4 __attribute__((ext_vector_type(4)));

// ---------- fused prep kernel ----------
// blocks [0, MDIM): per-row x quant (absmax scale + fp32 rowsum)
// blocks [MDIM, MDIM+NDIM): w int32 -> int8 pack (16 elems/thread)

__global__ __launch_bounds__(256) void prep(const float* __restrict__ x,
                                            const int* __restrict__ w,
                                            i8* __restrict__ xq,
                                            float* __restrict__ sx,
                                            float* __restrict__ xs,
                                            i8* __restrict__ w8) {
    const int t = threadIdx.x;
    if (blockIdx.x < MDIM) {
        __shared__ float ramax[4], rsum[4];
        const int row = blockIdx.x;
        const float* xr = x + (size_t)row * KDIM;
        const float4* p = (const float4*)xr + (t << 2);
        float4 v0 = p[0], v1 = p[1], v2 = p[2], v3 = p[3];
        float amax = 0.f, sum = 0.f;
        float vv[16] = {v0.x, v0.y, v0.z, v0.w, v1.x, v1.y, v1.z, v1.w,
                        v2.x, v2.y, v2.z, v2.w, v3.x, v3.y, v3.z, v3.w};
#pragma unroll
        for (int i = 0; i < 16; ++i) {
            amax = fmaxf(amax, fabsf(vv[i]));
            sum += vv[i];
        }
#pragma unroll
        for (int off = 32; off > 0; off >>= 1) {
            amax = fmaxf(amax, __shfl_down(amax, off, 64));
            sum += __shfl_down(sum, off, 64);
        }
        if ((t & 63) == 0) { ramax[t >> 6] = amax; rsum[t >> 6] = sum; }
        __syncthreads();
        amax = fmaxf(fmaxf(ramax[0], ramax[1]), fmaxf(ramax[2], ramax[3]));
        sum = (rsum[0] + rsum[1]) + (rsum[2] + rsum[3]);
        const float inv = (amax > 0.f) ? 127.0f / amax : 0.f;
        if (t == 0) {
            sx[row] = amax * (1.0f / 127.0f);
            xs[row] = sum;
        }
        i8 q[16];
#pragma unroll
        for (int i = 0; i < 16; ++i) q[i] = (i8)(int)rintf(vv[i] * inv);
        *(int4*)(xq + (size_t)row * KDIM + (t << 4)) = *(const int4*)q;
    } else {
        const size_t e = (((size_t)(blockIdx.x - MDIM) * 256 + t) << 4);
        const int4 a = *(const int4*)(w + e);
        const int4 b = *(const int4*)(w + e + 4);
        const int4 c = *(const int4*)(w + e + 8);
        const int4 d = *(const int4*)(w + e + 12);
        i8 q[16];
        q[0] = (i8)a.x; q[1] = (i8)a.y; q[2] = (i8)a.z; q[3] = (i8)a.w;
        q[4] = (i8)b.x; q[5] = (i8)b.y; q[6] = (i8)b.z; q[7] = (i8)b.w;
        q[8] = (i8)c.x; q[9] = (i8)c.y; q[10] = (i8)c.z; q[11] = (i8)c.w;
        q[12] = (i8)d.x; q[13] = (i8)d.y; q[14] = (i8)d.z; q[15] = (i8)d.w;
        *(int4*)(w8 + e) = *(const int4*)q;
    }
}

// ---------- GEMM (R7's verified kernel + stagger) ----------

__device__ __forceinline__ void gload16(const i8* g, i8* l) {
    __builtin_amdgcn_global_load_lds(
        (const __attribute__((address_space(1))) unsigned int*)g,
        (__attribute__((address_space(3))) unsigned int*)l, 16, 0, 0);
}

// A tile [256][64] = 16KB = 2 loads/thread; B tile [128][64] = 8KB = 1 load.
#define STAGE_A(T) do { const int _s = (T) % 3; const int _k = (T) * BK;          \
    gload16(gA0 + _k, &SH[_s][wid * 1024]);                                       \
    gload16(gA1 + _k, &SH[_s][8192 + wid * 1024]); } while (0)
#define STAGE_B(T) do { const int _s = (T) % 3; const int _k = (T) * BK;          \
    gload16(gB0 + _k, &SH[_s][BOFFS + wid * 1024]); } while (0)

// one K-tile group, R5/R7's 4-region structure: 2 phases of 8 MFMA each.
#define GROUP(T, DO_STAGE, WAITOP) do {                                           \
    const i8* _sA = &SH[(T) % 3][0];                                              \
    const i8* _sB = &SH[(T) % 3][BOFFS];                                          \
    i32x4 aF[2], bF[4], aG[2];                                                    \
    _Pragma("unroll") for (int _f = 0; _f < 2; ++_f)                              \
        aF[_f] = *(const i32x4*)(_sA + aoff + _f * 1024);                         \
    _Pragma("unroll") for (int _f = 0; _f < 4; ++_f)                              \
        bF[_f] = *(const i32x4*)(_sB + boff + _f * 1024);                         \
    if (DO_STAGE) STAGE_A((T) + 2);                                               \
    __builtin_amdgcn_s_barrier();                                                 \
    __builtin_amdgcn_s_setprio(1);                                                \
    _Pragma("unroll") for (int _i = 0; _i < 2; ++_i)                              \
    _Pragma("unroll") for (int _j = 0; _j < 4; ++_j)                              \
        acc[_i][_j] = __builtin_amdgcn_mfma_i32_16x16x64_i8(                      \
            aF[_i], bF[_j], acc[_i][_j], 0, 0, 0);                                \
    __builtin_amdgcn_s_setprio(0);                                                \
    __builtin_amdgcn_s_barrier();                                                 \
    _Pragma("unroll") for (int _f = 0; _f < 2; ++_f)                              \
        aG[_f] = *(const i32x4*)(_sA + aoff + (_f + 2) * 1024);                   \
    if (DO_STAGE) STAGE_B((T) + 2);                                               \
    __builtin_amdgcn_s_barrier();                                                 \
    __builtin_amdgcn_s_setprio(1);                                                \
    _Pragma("unroll") for (int _i = 0; _i < 2; ++_i)                              \
    _Pragma("unroll") for (int _j = 0; _j < 4; ++_j)                              \
        acc[_i + 2][_j] = __builtin_amdgcn_mfma_i32_16x16x64_i8(                  \
            aG[_i], bF[_j], acc[_i + 2][_j], 0, 0, 0);                            \
    __builtin_amdgcn_s_setprio(0);                                                \
    WAITOP;                                                                       \
    __builtin_amdgcn_s_barrier();                                                 \
} while (0)

__global__ __launch_bounds__(512, 4) void gemm_q(const i8* __restrict__ Xq,
                                                 const i8* __restrict__ Wq,
                                                 const float* __restrict__ sx,
                                                 const float* __restrict__ xs,
                                                 const float* __restrict__ scale,
                                                 const int* __restrict__ zp,
                                                 const float* __restrict__ bias,
                                                 float* __restrict__ out) {
    __shared__ __align__(16) i8 SH[3][SLOT];  // 72 KiB -> 2 blocks/CU

    const int tid = threadIdx.x;
    const int wid = tid >> 6;
    const int lane = tid & 63;

    // bijective XCD raster: xcd owns pm in [4*xcd, 4*xcd+4), pm-fastest in 4
    const int bid = blockIdx.x;
    const int off = bid >> 3;                       // 0..343
    const int pm = ((bid & 7) << 2) | (off & 3);    // 0..31
    const int pn = off >> 2;                        // 0..85
    const int bm0 = pm * BM;
    const int bn0 = pn * BN;

    // phase stagger: odd dispatch-round blocks start ~768cyc late so the two
    // co-resident blocks on a CU anti-phase their LDS/MFMA bursts.
    if ((bid >> 8) & 1) __builtin_amdgcn_s_sleep(12);

    // staging source: row = tid>>2, col pre-swizzled so that
    // physical[P] = logical[P ^ ((row&8)<<2)] with linear gload_lds dest.
    const int srow = tid >> 2;
    const int scol = ((tid & 3) << 4) ^ (((tid >> 5) & 1) << 5);
    const i8* gA0 = Xq + (size_t)(bm0 + srow) * KDIM + scol;
    const i8* gA1 = gA0 + (size_t)128 * KDIM;
    const i8* gB0 = Wq + (size_t)(bn0 + srow) * KDIM + scol;

    // wave map: 4M x 2N, per-wave output 64x64
    const int wm = wid >> 1, wn = wid & 1;
    const int lr = lane & 15;
    const int kb = (lane >> 4) << 4;            // 0,16,32,48 byte col
    const int swz = (lr & 8) << 2;              // row bit3 -> byte bit5
    const int aoff = (((wm * 64 + lr) << 6) + kb) ^ swz;
    const int boff = (((wn * 64 + lr) << 6) + kb) ^ swz;

    i32x4 acc[4][4];
#pragma unroll
    for (int i = 0; i < 4; ++i)
#pragma unroll
        for (int j = 0; j < 4; ++j) acc[i][j] = (i32x4){0, 0, 0, 0};

    // prologue: stage tiles 0,1; tile 0 landed at vmcnt(3)
    STAGE_A(0); STAGE_B(0);
    STAGE_A(1); STAGE_B(1);
    asm volatile("s_waitcnt vmcnt(3)" ::: "memory");
    __builtin_amdgcn_s_barrier();

    for (int t = 0; t < KT - 2; ++t) {  // stages tiles 2..63
        GROUP(t, true, asm volatile("s_waitcnt vmcnt(3)" ::: "memory"));
    }
    GROUP(KT - 2, false, asm volatile("s_waitcnt vmcnt(0)" ::: "memory"));
    GROUP(KT - 1, false, (void)0);

    // epilogue: C/D layout col = lane&15, row = (lane>>4)*4 + reg
    const int rr = (lane >> 4) << 2;
#pragma unroll
    for (int j = 0; j < 4; ++j) {
        const int n = bn0 + wn * 64 + j * 16 + lr;
        const float sc = scale[n];
        const float zpn = (float)zp[n];
        const float bi = bias[n];
#pragma unroll
        for (int i = 0; i < 4; ++i) {
            const int m = bm0 + wm * 64 + i * 16 + rr;
#pragma unroll
            for (int r = 0; r < 4; ++r) {
                const int mm = m + r;
                const float d = (float)acc[i][j][r];
                out[(size_t)mm * NDIM + n] = sc * (sx[mm] * d - zpn * xs[mm]) + bi;
            }
        }
    }
}

// ---------- fallback (ws too small) ----------

__global__ void naive_q(const float* __restrict__ x, const int* __restrict__ wq,
                        const float* __restrict__ scale, const int* __restrict__ zp,
                        const float* __restrict__ bias, float* __restrict__ out) {
    const long long idx = (long long)blockIdx.x * 256 + threadIdx.x;
    if (idx >= (long long)MDIM * NDIM) return;
    const int m = (int)(idx / NDIM);
    const int n = (int)(idx % NDIM);
    const float* xr = x + (long long)m * KDIM;
    const int* wr = wq + (long long)n * KDIM;
    float dot = 0.f, xsum = 0.f;
    for (int k = 0; k < KDIM; ++k) {
        dot += xr[k] * (float)wr[k];
        xsum += xr[k];
    }
    out[idx] = scale[n] * (dot - (float)zp[n] * xsum) + bias[n];
}

extern "C" void kernel_launch(void* const* d_in, const int* in_sizes, int n_in,
                              void* d_out, int out_size, void* d_ws, size_t ws_size,
                              hipStream_t stream) {
    const float* x = (const float*)d_in[0];
    const int* wq = (const int*)d_in[1];
    const float* scale = (const float*)d_in[2];
    const int* zp = (const int*)d_in[3];
    const float* bias = (const float*)d_in[4];
    float* out = (float*)d_out;

    const size_t w8_bytes = (size_t)NDIM * KDIM;      // 45,088,768
    const size_t xq_bytes = (size_t)MDIM * KDIM;      // 33,554,432
    const size_t row_bytes = (size_t)MDIM * 4;        // 32,768
    const size_t need = w8_bytes + xq_bytes + 2 * row_bytes;

    if (ws_size >= need) {
        i8* w8 = (i8*)d_ws;
        i8* xq8 = (i8*)((char*)d_ws + w8_bytes);
        float* sx = (float*)((char*)d_ws + w8_bytes + xq_bytes);
        float* xs = (float*)((char*)d_ws + w8_bytes + xq_bytes + row_bytes);
        // fused prep: blocks [0,MDIM) quantize x rows; [MDIM, MDIM+NDIM) pack w
        prep<<<MDIM + NDIM, 256, 0, stream>>>(x, wq, xq8, sx, xs, w8);
        gemm_q<<<NWG, 512, 0, stream>>>(xq8, w8, sx, xs, scale, zp, bias, out);
    } else {
        const long long total = (long long)MDIM * NDIM;
        naive_q<<<(unsigned)((total + 255) / 256), 256, 0, stream>>>(
            x, wq, scale, zp, bias, out);
    }
}

// Round 11
// 535.097 us; speedup vs baseline: 1.0576x; 1.0016x over previous
//
#include <hip/hip_runtime.h>
#include <hip/hip_bf16.h>

// CustomQuantLinear: out[m][n] = scale[n] * sum_k x[m][k]*(w[n][k]-zp[n]) + bias[n]
// M=8192, N=11008, K=4096.
// R10 -> R11: six schedules converge at ~3168 cyc per 256^2xK64 tile (within
// 6% of the best-known plain-HIP structure wall, m201's ~2983). GEMM kept
// exactly as R7/R10 (best measured). Changes: (1) prep loads made lane-
// contiguous (old layout had 64B lane stride -> 4x transaction inflation);
// (2) dead s_sleep stagger removed (measured null).

#define MDIM 8192
#define NDIM 11008
#define KDIM 4096

#define BM 256
#define BN 128
#define BK 64
#define KT (KDIM / BK)   // 64
#define NTM (MDIM / BM)  // 32
#define NTN (NDIM / BN)  // 86
#define NWG (NTM * NTN)  // 2752 = 8*344

#define SLOT 24576       // 16KB A + 8KB B
#define BOFFS 16384      // B region offset within slot

typedef signed char i8;
typedef int i32x4 __attribute__((ext_vector_type(4)));

// ---------- fused prep kernel (coalesced) ----------
// blocks [0, MDIM): per-row x quant (absmax scale + fp32 rowsum)
// blocks [MDIM, MDIM+NDIM): w int32 -> int8 pack
// Thread t owns elements {k*1024 + 4t .. +3}, k=0..3: every 16B vector load is
// lane-contiguous (1KB/instr coalesced); 4B packed writes (256B/wave).

__global__ __launch_bounds__(256) void prep(const float* __restrict__ x,
                                            const int* __restrict__ w,
                                            i8* __restrict__ xq,
                                            float* __restrict__ sx,
                                            float* __restrict__ xs,
                                            i8* __restrict__ w8) {
    const int t = threadIdx.x;
    if (blockIdx.x < MDIM) {
        __shared__ float ramax[4], rsum[4];
        const int row = blockIdx.x;
        const float* xr = x + (size_t)row * KDIM;
        float4 v[4];
#pragma unroll
        for (int k = 0; k < 4; ++k) v[k] = *((const float4*)(xr + k * 1024) + t);
        float amax = 0.f, sum = 0.f;
#pragma unroll
        for (int k = 0; k < 4; ++k) {
            amax = fmaxf(amax, fmaxf(fmaxf(fabsf(v[k].x), fabsf(v[k].y)),
                                     fmaxf(fabsf(v[k].z), fabsf(v[k].w))));
            sum += (v[k].x + v[k].y) + (v[k].z + v[k].w);
        }
#pragma unroll
        for (int off = 32; off > 0; off >>= 1) {
            amax = fmaxf(amax, __shfl_down(amax, off, 64));
            sum += __shfl_down(sum, off, 64);
        }
        if ((t & 63) == 0) { ramax[t >> 6] = amax; rsum[t >> 6] = sum; }
        __syncthreads();
        amax = fmaxf(fmaxf(ramax[0], ramax[1]), fmaxf(ramax[2], ramax[3]));
        sum = (rsum[0] + rsum[1]) + (rsum[2] + rsum[3]);
        const float inv = (amax > 0.f) ? 127.0f / amax : 0.f;
        if (t == 0) {
            sx[row] = amax * (1.0f / 127.0f);
            xs[row] = sum;
        }
        i8* xqr = xq + (size_t)row * KDIM;
#pragma unroll
        for (int k = 0; k < 4; ++k) {
            i8 q[4];
            q[0] = (i8)(int)rintf(v[k].x * inv);
            q[1] = (i8)(int)rintf(v[k].y * inv);
            q[2] = (i8)(int)rintf(v[k].z * inv);
            q[3] = (i8)(int)rintf(v[k].w * inv);
            *(int*)(xqr + k * 1024 + (t << 2)) = *(const int*)q;
        }
    } else {
        const size_t base = (size_t)(blockIdx.x - MDIM) * 4096;
#pragma unroll
        for (int k = 0; k < 4; ++k) {
            const int4 a = *((const int4*)(w + base + k * 1024) + t);
            i8 q[4] = {(i8)a.x, (i8)a.y, (i8)a.z, (i8)a.w};
            *(int*)(w8 + base + k * 1024 + (t << 2)) = *(const int*)q;
        }
    }
}

// ---------- GEMM (R7/R10's verified kernel, stagger removed) ----------

__device__ __forceinline__ void gload16(const i8* g, i8* l) {
    __builtin_amdgcn_global_load_lds(
        (const __attribute__((address_space(1))) unsigned int*)g,
        (__attribute__((address_space(3))) unsigned int*)l, 16, 0, 0);
}

// A tile [256][64] = 16KB = 2 loads/thread; B tile [128][64] = 8KB = 1 load.
#define STAGE_A(T) do { const int _s = (T) % 3; const int _k = (T) * BK;          \
    gload16(gA0 + _k, &SH[_s][wid * 1024]);                                       \
    gload16(gA1 + _k, &SH[_s][8192 + wid * 1024]); } while (0)
#define STAGE_B(T) do { const int _s = (T) % 3; const int _k = (T) * BK;          \
    gload16(gB0 + _k, &SH[_s][BOFFS + wid * 1024]); } while (0)

// one K-tile group, R5/R7's 4-region structure: 2 phases of 8 MFMA each.
#define GROUP(T, DO_STAGE, WAITOP) do {                                           \
    const i8* _sA = &SH[(T) % 3][0];                                              \
    const i8* _sB = &SH[(T) % 3][BOFFS];                                          \
    i32x4 aF[2], bF[4], aG[2];                                                    \
    _Pragma("unroll") for (int _f = 0; _f < 2; ++_f)                              \
        aF[_f] = *(const i32x4*)(_sA + aoff + _f * 1024);                         \
    _Pragma("unroll") for (int _f = 0; _f < 4; ++_f)                              \
        bF[_f] = *(const i32x4*)(_sB + boff + _f * 1024);                         \
    if (DO_STAGE) STAGE_A((T) + 2);                                               \
    __builtin_amdgcn_s_barrier();                                                 \
    __builtin_amdgcn_s_setprio(1);                                                \
    _Pragma("unroll") for (int _i = 0; _i < 2; ++_i)                              \
    _Pragma("unroll") for (int _j = 0; _j < 4; ++_j)                              \
        acc[_i][_j] = __builtin_amdgcn_mfma_i32_16x16x64_i8(                      \
            aF[_i], bF[_j], acc[_i][_j], 0, 0, 0);                                \
    __builtin_amdgcn_s_setprio(0);                                                \
    __builtin_amdgcn_s_barrier();                                                 \
    _Pragma("unroll") for (int _f = 0; _f < 2; ++_f)                              \
        aG[_f] = *(const i32x4*)(_sA + aoff + (_f + 2) * 1024);                   \
    if (DO_STAGE) STAGE_B((T) + 2);                                               \
    __builtin_amdgcn_s_barrier();                                                 \
    __builtin_amdgcn_s_setprio(1);                                                \
    _Pragma("unroll") for (int _i = 0; _i < 2; ++_i)                              \
    _Pragma("unroll") for (int _j = 0; _j < 4; ++_j)                              \
        acc[_i + 2][_j] = __builtin_amdgcn_mfma_i32_16x16x64_i8(                  \
            aG[_i], bF[_j], acc[_i + 2][_j], 0, 0, 0);                            \
    __builtin_amdgcn_s_setprio(0);                                                \
    WAITOP;                                                                       \
    __builtin_amdgcn_s_barrier();                                                 \
} while (0)

__global__ __launch_bounds__(512, 4) void gemm_q(const i8* __restrict__ Xq,
                                                 const i8* __restrict__ Wq,
                                                 const float* __restrict__ sx,
                                                 const float* __restrict__ xs,
                                                 const float* __restrict__ scale,
                                                 const int* __restrict__ zp,
                                                 const float* __restrict__ bias,
                                                 float* __restrict__ out) {
    __shared__ __align__(16) i8 SH[3][SLOT];  // 72 KiB -> 2 blocks/CU

    const int tid = threadIdx.x;
    const int wid = tid >> 6;
    const int lane = tid & 63;

    // bijective XCD raster: xcd owns pm in [4*xcd, 4*xcd+4), pm-fastest in 4
    const int bid = blockIdx.x;
    const int off = bid >> 3;                       // 0..343
    const int pm = ((bid & 7) << 2) | (off & 3);    // 0..31
    const int pn = off >> 2;                        // 0..85
    const int bm0 = pm * BM;
    const int bn0 = pn * BN;

    // staging source: row = tid>>2, col pre-swizzled so that
    // physical[P] = logical[P ^ ((row&8)<<2)] with linear gload_lds dest.
    const int srow = tid >> 2;
    const int scol = ((tid & 3) << 4) ^ (((tid >> 5) & 1) << 5);
    const i8* gA0 = Xq + (size_t)(bm0 + srow) * KDIM + scol;
    const i8* gA1 = gA0 + (size_t)128 * KDIM;
    const i8* gB0 = Wq + (size_t)(bn0 + srow) * KDIM + scol;

    // wave map: 4M x 2N, per-wave output 64x64
    const int wm = wid >> 1, wn = wid & 1;
    const int lr = lane & 15;
    const int kb = (lane >> 4) << 4;            // 0,16,32,48 byte col
    const int swz = (lr & 8) << 2;              // row bit3 -> byte bit5
    const int aoff = (((wm * 64 + lr) << 6) + kb) ^ swz;
    const int boff = (((wn * 64 + lr) << 6) + kb) ^ swz;

    i32x4 acc[4][4];
#pragma unroll
    for (int i = 0; i < 4; ++i)
#pragma unroll
        for (int j = 0; j < 4; ++j) acc[i][j] = (i32x4){0, 0, 0, 0};

    // prologue: stage tiles 0,1; tile 0 landed at vmcnt(3)
    STAGE_A(0); STAGE_B(0);
    STAGE_A(1); STAGE_B(1);
    asm volatile("s_waitcnt vmcnt(3)" ::: "memory");
    __builtin_amdgcn_s_barrier();

    for (int t = 0; t < KT - 2; ++t) {  // stages tiles 2..63
        GROUP(t, true, asm volatile("s_waitcnt vmcnt(3)" ::: "memory"));
    }
    GROUP(KT - 2, false, asm volatile("s_waitcnt vmcnt(0)" ::: "memory"));
    GROUP(KT - 1, false, (void)0);

    // epilogue: C/D layout col = lane&15, row = (lane>>4)*4 + reg
    const int rr = (lane >> 4) << 2;
#pragma unroll
    for (int j = 0; j < 4; ++j) {
        const int n = bn0 + wn * 64 + j * 16 + lr;
        const float sc = scale[n];
        const float zpn = (float)zp[n];
        const float bi = bias[n];
#pragma unroll
        for (int i = 0; i < 4; ++i) {
            const int m = bm0 + wm * 64 + i * 16 + rr;
#pragma unroll
            for (int r = 0; r < 4; ++r) {
                const int mm = m + r;
                const float d = (float)acc[i][j][r];
                out[(size_t)mm * NDIM + n] = sc * (sx[mm] * d - zpn * xs[mm]) + bi;
            }
        }
    }
}

// ---------- fallback (ws too small) ----------

__global__ void naive_q(const float* __restrict__ x, const int* __restrict__ wq,
                        const float* __restrict__ scale, const int* __restrict__ zp,
                        const float* __restrict__ bias, float* __restrict__ out) {
    const long long idx = (long long)blockIdx.x * 256 + threadIdx.x;
    if (idx >= (long long)MDIM * NDIM) return;
    const int m = (int)(idx / NDIM);
    const int n = (int)(idx % NDIM);
    const float* xr = x + (long long)m * KDIM;
    const int* wr = wq + (long long)n * KDIM;
    float dot = 0.f, xsum = 0.f;
    for (int k = 0; k < KDIM; ++k) {
        dot += xr[k] * (float)wr[k];
        xsum += xr[k];
    }
    out[idx] = scale[n] * (dot - (float)zp[n] * xsum) + bias[n];
}

extern "C" void kernel_launch(void* const* d_in, const int* in_sizes, int n_in,
                              void* d_out, int out_size, void* d_ws, size_t ws_size,
                              hipStream_t stream) {
    const float* x = (const float*)d_in[0];
    const int* wq = (const int*)d_in[1];
    const float* scale = (const float*)d_in[2];
    const int* zp = (const int*)d_in[3];
    const float* bias = (const float*)d_in[4];
    float* out = (float*)d_out;

    const size_t w8_bytes = (size_t)NDIM * KDIM;      // 45,088,768
    const size_t xq_bytes = (size_t)MDIM * KDIM;      // 33,554,432
    const size_t row_bytes = (size_t)MDIM * 4;        // 32,768
    const size_t need = w8_bytes + xq_bytes + 2 * row_bytes;

    if (ws_size >= need) {
        i8* w8 = (i8*)d_ws;
        i8* xq8 = (i8*)((char*)d_ws + w8_bytes);
        float* sx = (float*)((char*)d_ws + w8_bytes + xq_bytes);
        float* xs = (float*)((char*)d_ws + w8_bytes + xq_bytes + row_bytes);
        // fused prep: blocks [0,MDIM) quantize x rows; [MDIM, MDIM+NDIM) pack w
        prep<<<MDIM + NDIM, 256, 0, stream>>>(x, wq, xq8, sx, xs, w8);
        gemm_q<<<NWG, 512, 0, stream>>>(xq8, w8, sx, xs, scale, zp, bias, out);
    } else {
        const long long total = (long long)MDIM * NDIM;
        naive_q<<<(unsigned)((total + 255) / 256), 256, 0, stream>>>(
            x, wq, scale, zp, bias, out);
    }
}